// Round 8
// baseline (458.472 us; speedup 1.0000x reference)
//
#include <hip/hip_runtime.h>

// Problem constants
#define B_ 16
#define C_ 256
#define T_ 2048
#define K_ 8192
#define D_ 256
#define N_ (B_ * T_)                 // 32768 rows
#define OUTQ ((size_t)B_ * C_ * T_)  // 8388608 quantized elements

#define BM 64                        // rows per argmin block
#define CHUNK 64                     // codes per LDS chunk (32KB)
#define NCHUNK (K_ / CHUNK)          // 128
#define NTHR 256                     // 4 waves = 4 code-groups, each owns all rows
// Phase-1 margin (biased-mm units). Worst-case bf16 2*2^-9*||x||*||e|| <=1.77e-4
// + pack quant 6.1e-5 + fp32 bin slack 3.2e-5 = 2.7e-4 < 4e-4.
#define MARGINF 4e-4f
#define BIASF 0.03125f               // 2^-5, folded into MFMA acc init
#define QCAP 512

typedef __attribute__((ext_vector_type(8))) short bf16x8;   // 8 bf16 = 4 VGPR
typedef __attribute__((ext_vector_type(4))) float f32x4;

__device__ __forceinline__ unsigned f2bf(float f) {         // RTNE f32->bf16
  unsigned u = __float_as_uint(f);
  return (u + 0x7FFFu + ((u >> 16) & 1u)) >> 16;
}
__device__ __forceinline__ unsigned umin_(unsigned a, unsigned b){return a<b?a:b;}
__device__ __forceinline__ unsigned umax_(unsigned a, unsigned b){return a>b?a:b;}

#define GLDS(g, l) __builtin_amdgcn_global_load_lds( \
    (const __attribute__((address_space(1))) void*)(g), \
    (__attribute__((address_space(3))) void*)(l), 16, 0, 0)

// ---------------------------------------------------------------------------
// Prep: E fp32 -> bf16, XOR-16 swizzle PRE-APPLIED in global memory so that
// global_load_lds (linear) lands it swizzled in LDS (T2 both-sides rule).
// Element (code,d) bf16 stored at byte: code*512 + ((2d) ^ ((code&15)<<4)).
// ---------------------------------------------------------------------------
__global__ __launch_bounds__(256) void ebf_prep_kernel(
    const float* __restrict__ emb, unsigned char* __restrict__ ebf)
{
  int gid  = blockIdx.x * 256 + threadIdx.x;    // 8192 codes x 64 quads
  int code = gid >> 6, dq = gid & 63;
  float4 v = *reinterpret_cast<const float4*>(emb + (size_t)code * D_ + dq * 4);
  unsigned lo = f2bf(v.x) | (f2bf(v.y) << 16);
  unsigned hi = f2bf(v.z) | (f2bf(v.w) << 16);
  unsigned off = code * 512 + ((dq * 8) ^ ((code & 15) << 4));
  *reinterpret_cast<uint2*>(ebf + off) = make_uint2(lo, hi);
}

// ---------------------------------------------------------------------------
// Argmin. OCCUPANCY DESIGN (rounds 4/5/7 measured): a 512-thr block caps
// arch-VGPR at 128 and spills the 128-VGPR resident A array (74MB scratch
// traffic); a 256-thr block compiles to 200 VGPR spill-free. So: 256-thr
// blocks, BM=64, grid=512 -> 2 INDEPENDENT blocks/CU = 2 waves/SIMD, with
// staggered (per-block) barriers so one block computes while the other
// drains its chunk-boundary vmcnt.
// Phase 1: bf16 MFMA GEMM (A resident, B=E chunks via swizzled
// global_load_lds dbuf), per-(lane,slot) top-2 of packed (q(mm+BIAS)|k).
// Phase 2: exact fp32-rounding-emulated refine of candidates within MARGINF
// of the row max (sequential-fp32 x2/e2, fp64 dot, fl-exact dist), worklist
// balanced one-per-lane, first-index ties via packed atomicMin.
// ---------------------------------------------------------------------------
__global__ __launch_bounds__(NTHR, 1) void vq_argmin_kernel(
    const float* __restrict__ lat, const float* __restrict__ emb,
    const unsigned char* __restrict__ ebf, int* __restrict__ idx_out,
    float* __restrict__ idxf_out)
{
  __shared__ __align__(16) unsigned char Ebuf[2][CHUNK * 512];  // 64KB dbuf
  __shared__ unsigned rmaxU[4][BM];
  __shared__ unsigned long long bestp[BM];
  __shared__ unsigned qlist[QCAP];
  __shared__ int qn;

  const int tid  = threadIdx.x;
  const int lane = tid & 63;
  const int w    = tid >> 6;       // wave 0..3 = code group
  const int cg   = w;              // 16 codes of each 64-chunk
  const int kg   = lane >> 4;      // k-group 0..3 (16x16x32 A/B k map)
  const int l15  = lane & 15;

  const int n0    = blockIdx.x * BM;
  const int bb    = n0 >> 11;                  // batch (BM | 2048)
  const int tbase = n0 & (T_ - 1);
  const float* latb = lat + (size_t)bb * C_ * T_;

  if (tid == 0) qn = 0;
  if (tid < BM) bestp[tid] = ~0ull;

  // prefetch chunk 0 (each wave DMAs its 8KB slice; lane*16 on SOURCE only)
  {
    const unsigned char* src = ebf + w * 8192 + lane * 16;
    unsigned char* dst = &Ebuf[0][w * 8192];
    #pragma unroll
    for (int j = 0; j < 8; ++j) GLDS(src + j * 1024, dst + j * 1024);
  }

  // ---- A fragments: all 64 rows x 256 dims bf16, resident (128 VGPR) ----
  // A map: row = lane&15 (+rf*16), k = (lane>>4)*8 + j (+ks*32)
  bf16x8 A[4][8];
  #pragma unroll
  for (int rf = 0; rf < 4; ++rf) {
    const int t = tbase + rf * 16 + l15;
    const float* lp = latb + t;
    #pragma unroll
    for (int ks = 0; ks < 8; ++ks) {
      const int c0 = ks * 32 + kg * 8;
      bf16x8 a;
      #pragma unroll
      for (int j = 0; j < 8; ++j)
        a[j] = (short)f2bf(lp[(size_t)(c0 + j) * T_]);   // coalesced across l15
      A[rf][ks] = a;
    }
  }
  __syncthreads();   // drains chunk-0 DMA

  unsigned m1[16], m2[16];
  #pragma unroll
  for (int s = 0; s < 16; ++s) { m1[s] = 0u; m2[s] = 0u; }
  const unsigned kv0 = cg * 16 + l15;

  for (int ch = 0; ch < NCHUNK; ++ch) {
    const int pb = ch & 1;
    if (ch + 1 < NCHUNK) {       // prefetch next chunk into other buffer
      const unsigned char* src =
          ebf + (size_t)(ch + 1) * (CHUNK * 512) + w * 8192 + lane * 16;
      unsigned char* dst = &Ebuf[pb ^ 1][w * 8192];
      #pragma unroll
      for (int j = 0; j < 8; ++j) GLDS(src + j * 1024, dst + j * 1024);
    }

    // B fragments: col = lane&15, k = (lane>>4)*8+j — swizzled, conflict-free
    const unsigned char* bbase = &Ebuf[pb][0];
    const int code_l = cg * 16 + l15;
    bf16x8 Bf[8];
    #pragma unroll
    for (int ks = 0; ks < 8; ++ks) {
      const unsigned off = code_l * 512 + ((ks * 64 + kg * 16) ^ (l15 << 4));
      Bf[ks] = *reinterpret_cast<const bf16x8*>(bbase + off);
    }
    const unsigned kv = kv0 + (unsigned)(ch * CHUNK);
    #pragma unroll
    for (int rf = 0; rf < 4; ++rf) {
      f32x4 acc = {BIASF, BIASF, BIASF, BIASF};     // BIAS folded into C-init
      #pragma unroll
      for (int ks = 0; ks < 8; ++ks)
        acc = __builtin_amdgcn_mfma_f32_16x16x32_bf16(A[rf][ks], Bf[ks],
                                                      acc, 0, 0, 0);
      #pragma unroll
      for (int r = 0; r < 4; ++r) {     // C: col=lane&15, row=(lane>>4)*4+r
        const unsigned p = (__float_as_uint(acc[r]) & 0xFFFFE000u) | kv;
        const int s = rf * 4 + r;
        const unsigned mn = umin_(p, m1[s]);
        m1[s] = umax_(p, m1[s]);
        m2[s] = umax_(m2[s], mn);
      }
    }
    __syncthreads();   // drain DMA(ch+1), release Ebuf[pb]
  }

  // ---- row max: reduce over lane&15 (16 lanes hold same row set) ----
  #pragma unroll
  for (int s = 0; s < 16; ++s) {
    unsigned v = m1[s];
    v = umax_(v, __shfl_xor(v, 1));
    v = umax_(v, __shfl_xor(v, 2));
    v = umax_(v, __shfl_xor(v, 4));
    v = umax_(v, __shfl_xor(v, 8));
    const int row = (s >> 2) * 16 + kg * 4 + (s & 3);
    rmaxU[cg][row] = v;                 // 16 lanes write same value: benign
  }
  __syncthreads();

  // ---- candidate emission (load-balanced worklist) ----
  #pragma unroll
  for (int s = 0; s < 16; ++s) {
    const int row = (s >> 2) * 16 + kg * 4 + (s & 3);
    const unsigned rm = umax_(umax_(rmaxU[0][row], rmaxU[1][row]),
                              umax_(rmaxU[2][row], rmaxU[3][row]));
    const float thr = __uint_as_float(rm & 0xFFFFE000u) - MARGINF;
    #pragma unroll
    for (int which = 0; which < 2; ++which) {
      const unsigned m = which ? m2[s] : m1[s];
      if (__uint_as_float(m & 0xFFFFE000u) >= thr) {
        int id = atomicAdd(&qn, 1);
        if (id < QCAP) qlist[id] = ((unsigned)row << 13) | (m & 0x1FFFu);
      }
    }
  }
  __syncthreads();

  // ---- phase 2: exact refine, one candidate per lane ----
  const int nq = qn < QCAP ? qn : QCAP;
  for (int i = tid; i < nq; i += NTHR) {
    const unsigned e = qlist[i];
    const int row = (int)(e >> 13);
    const int k   = (int)(e & 0x1FFFu);
    const int t   = tbase + row;
    const float* xp = latb + t;
    const float* ep = emb + (size_t)k * D_;
    float x2 = 0.f, e2 = 0.f;
    double da = 0.0;
    {
      #pragma clang fp contract(off)
      for (int c = 0; c < D_; ++c) {
        const float xv = xp[(size_t)c * T_];
        const float ev = ep[c];
        const float xs = xv * xv; x2 = x2 + xs;   // sequential fp32, ref order
        const float es = ev * ev; e2 = e2 + es;
        da = fma((double)xv, (double)ev, da);
      }
    }
    float dist;
    {
      #pragma clang fp contract(off)
      const float mmf = (float)da;     // mm rounded to fp32
      const float tk  = x2 + e2;       // fl(x2 + e2)
      const float two = 2.0f * mmf;    // exact
      dist = tk - two;                 // final fp32 rounding
    }
    const unsigned long long pk =
        ((unsigned long long)__float_as_uint(dist) << 32) | (unsigned)k;
    atomicMin(&bestp[row], pk);        // first-index tie-break via low bits
  }
  __syncthreads();
  if (tid < BM) {
    const int k = (int)(bestp[tid] & 0xFFFFFFFFu);
    idx_out[n0 + tid]  = k;
    idxf_out[n0 + tid] = (float)k;     // float idx output folded in
  }
}

// ---------------------------------------------------------------------------
// Output gather + loss partials. Block = (b, 64-t chunk). The 64 needed emb
// rows are staged in LDS via fully-coalesced float4 reads (1KB bursts) into a
// [c][r] layout (+1 pad) so the write phase reads conflict-free; lat reads and
// outq writes stay coalesced over t.
// ---------------------------------------------------------------------------
__global__ __launch_bounds__(256) void vq_out_kernel(
    const float* __restrict__ lat, const float* __restrict__ emb,
    const int* __restrict__ idx, float* __restrict__ outq,
    double* __restrict__ partial)
{
  __shared__ float Ecol[256][65];      // [c][r], 66.6KB
  __shared__ double sred[256];
  const int gid = blockIdx.x;          // b(16) x tc(32)
  const int b   = gid >> 5;
  const int t0  = (gid & 31) * 64;

  // stage: 16 iters x 4 rows; r uniform per wave, c4 = lane
  {
    const int r4 = threadIdx.x >> 6, c4 = threadIdx.x & 63;
    for (int it = 0; it < 16; ++it) {
      const int r = it * 4 + r4;
      const int n = idx[b * T_ + t0 + r];
      const float4 v =
          *reinterpret_cast<const float4*>(emb + (size_t)n * D_ + c4 * 4);
      Ecol[c4 * 4 + 0][r] = v.x;
      Ecol[c4 * 4 + 1][r] = v.y;
      Ecol[c4 * 4 + 2][r] = v.z;
      Ecol[c4 * 4 + 3][r] = v.w;
    }
  }
  __syncthreads();

  const int cq = threadIdx.x >> 6, tl = threadIdx.x & 63;
  const int t  = t0 + tl;
  double lsum = 0.0;
  for (int ci = 0; ci < 64; ++ci) {
    const int c = cq * 64 + ci;
    const size_t off = ((size_t)b * C_ + c) * T_ + t;
    const float q = Ecol[c][tl];       // bank = (c + tl) % 32: conflict-free
    const float l = lat[off];
    outq[off] = q;
    const double d = (double)q - (double)l;
    lsum += d * d;
  }
  sred[threadIdx.x] = lsum;
  __syncthreads();
  for (int s = 128; s > 0; s >>= 1) {
    if (threadIdx.x < s) sred[threadIdx.x] += sred[threadIdx.x + s];
    __syncthreads();
  }
  if (threadIdx.x == 0) partial[gid] = sred[0];
}

__global__ __launch_bounds__(256) void vq_loss_kernel(
    const double* __restrict__ partial, float* __restrict__ out_loss)
{
  __shared__ double sred[256];
  double s = 0.0;
  for (int i = threadIdx.x; i < 512; i += 256) s += partial[i];
  sred[threadIdx.x] = s;
  __syncthreads();
  for (int st = 128; st > 0; st >>= 1) {
    if (threadIdx.x < st) sred[threadIdx.x] += sred[threadIdx.x + st];
    __syncthreads();
  }
  if (threadIdx.x == 0) {
    double m = sred[0] / (double)OUTQ;
    out_loss[0] = (float)(m + 0.25 * m);
  }
}

extern "C" void kernel_launch(void* const* d_in, const int* in_sizes, int n_in,
                              void* d_out, int out_size, void* d_ws, size_t ws_size,
                              hipStream_t stream)
{
  const float* lat = (const float*)d_in[0];   // [B, C, T] fp32
  const float* emb = (const float*)d_in[1];   // [K, D] fp32

  float* outq     = (float*)d_out;            // [B, C, T]
  float* out_loss = outq + OUTQ;              // scalar
  float* out_idx  = outq + OUTQ + 1;          // [B, T] as float

  // 4MB swizzled-bf16 E scratch overlaid on outq (dead before vq_out writes)
  unsigned char* ebf = (unsigned char*)d_out;
  // small scratch in ws: idx (128KB) + partials (4KB)
  int*    idx     = (int*)d_ws;
  double* partial = (double*)((char*)d_ws + (size_t)N_ * sizeof(int));

  ebf_prep_kernel  <<<2048,    256,  0, stream>>>(emb, ebf);
  vq_argmin_kernel <<<N_ / BM, NTHR, 0, stream>>>(lat, emb, ebf, idx, out_idx);
  vq_out_kernel    <<<512,     256,  0, stream>>>(lat, emb, idx, outq, partial);
  vq_loss_kernel   <<<1,       256,  0, stream>>>(partial, out_loss);
}

// Round 11
// 314.585 us; speedup vs baseline: 1.4574x; 1.4574x over previous
//
#include <hip/hip_runtime.h>

// Problem constants
#define B_ 16
#define C_ 256
#define T_ 2048
#define K_ 8192
#define D_ 256
#define N_ (B_ * T_)                 // 32768 rows
#define OUTQ ((size_t)B_ * C_ * T_)  // 8388608 quantized elements

#define BM 64                        // rows per argmin block (2 rg x 32)
#define CHUNK 64                     // codes per LDS chunk (32KB)
#define NCHUNK (K_ / CHUNK)          // 128
#define NTHR 256                     // 4 waves: 2 row-groups x 2 code-groups
// Phase-1 margin (biased-mm units). Worst-case bf16 2*2^-9*||x||*||e|| <=1.77e-4
// + pack quant 6.1e-5 + fp32 bin slack 3.2e-5 = 2.7e-4 < 4e-4.
#define MARGINF 4e-4f
#define BIASF 0.03125f               // 2^-5, folded into MFMA acc init
#define QCAP 512

typedef __attribute__((ext_vector_type(8))) short bf16x8;   // 8 bf16 = 4 VGPR
typedef __attribute__((ext_vector_type(4))) float f32x4;

__device__ __forceinline__ unsigned f2bf(float f) {         // RTNE f32->bf16
  unsigned u = __float_as_uint(f);
  return (u + 0x7FFFu + ((u >> 16) & 1u)) >> 16;
}
__device__ __forceinline__ unsigned umin_(unsigned a, unsigned b){return a<b?a:b;}
__device__ __forceinline__ unsigned umax_(unsigned a, unsigned b){return a>b?a:b;}

#define GLDS(g, l) __builtin_amdgcn_global_load_lds( \
    (const __attribute__((address_space(1))) void*)(g), \
    (__attribute__((address_space(3))) void*)(l), 16, 0, 0)

// ---------------------------------------------------------------------------
// Prep: E fp32 -> bf16, XOR-16 swizzle PRE-APPLIED in global memory so that
// global_load_lds (linear) lands it swizzled in LDS (T2 both-sides rule).
// Element (code,d) bf16 stored at byte: code*512 + ((2d) ^ ((code&15)<<4)).
// ---------------------------------------------------------------------------
__global__ __launch_bounds__(256) void ebf_prep_kernel(
    const float* __restrict__ emb, unsigned char* __restrict__ ebf)
{
  int gid  = blockIdx.x * 256 + threadIdx.x;    // 8192 codes x 64 quads
  int code = gid >> 6, dq = gid & 63;
  float4 v = *reinterpret_cast<const float4*>(emb + (size_t)code * D_ + dq * 4);
  unsigned lo = f2bf(v.x) | (f2bf(v.y) << 16);
  unsigned hi = f2bf(v.z) | (f2bf(v.w) << 16);
  unsigned off = code * 512 + ((dq * 8) ^ ((code & 15) << 4));
  *reinterpret_cast<uint2*>(ebf + off) = make_uint2(lo, hi);
}

// ---------------------------------------------------------------------------
// Argmin. OCCUPANCY DESIGN (rounds 4/5/7/8 measured): per-wave arch+AGPR
// must be <=256 for 2 waves/SIMD; rocprof VGPR_Count is arch-only (round 8:
// 200 arch + agpr > 256 -> 1 wave/SIMD, 2nd block never co-scheduled).
// So: halve A residency. 4 waves = 2 row-groups x 2 code-groups; each wave
// owns 32 rows (A[2][8] = 64 VGPR) x 32 codes/chunk. ~150-170 total/wave ->
// 2 blocks/CU (LDS 68.6KB) = 2 waves/SIMD with INDEPENDENT barriers.
// Phase 1: bf16 MFMA GEMM, per-(lane,slot) top-2 of packed (q(mm+BIAS)|k).
// Phase 2: exact fp32-rounding-emulated refine of candidates within MARGINF
// of the row max (sequential-fp32 x2/e2, fp64 dot, fl-exact dist), worklist
// one-per-lane, first-index ties via packed atomicMin.
// ---------------------------------------------------------------------------
__global__ __launch_bounds__(NTHR) void vq_argmin_kernel(
    const float* __restrict__ lat, const float* __restrict__ emb,
    const unsigned char* __restrict__ ebf, int* __restrict__ idx_out,
    float* __restrict__ idxf_out)
{
  __shared__ __align__(16) unsigned char Ebuf[2][CHUNK * 512];  // 64KB dbuf
  __shared__ unsigned rmaxU[2][BM];
  __shared__ unsigned long long bestp[BM];
  __shared__ unsigned qlist[QCAP];
  __shared__ int qn;

  const int tid  = threadIdx.x;
  const int lane = tid & 63;
  const int w    = tid >> 6;       // wave 0..3
  const int rg   = w >> 1;         // row group (32 rows)
  const int cg   = w & 1;          // code group (32 codes of the 64-chunk)
  const int kg   = lane >> 4;      // k-group 0..3 (16x16x32 A/B k map)
  const int l15  = lane & 15;

  const int n0    = blockIdx.x * BM;
  const int bb    = n0 >> 11;                  // batch (BM | 2048)
  const int tbase = n0 & (T_ - 1);
  const float* latb = lat + (size_t)bb * C_ * T_;

  if (tid == 0) qn = 0;
  if (tid < BM) bestp[tid] = ~0ull;

  // prefetch chunk 0 (each wave DMAs its 8KB slice; lane*16 on SOURCE only)
  {
    const unsigned char* src = ebf + w * 8192 + lane * 16;
    unsigned char* dst = &Ebuf[0][w * 8192];
    #pragma unroll
    for (int j = 0; j < 8; ++j) GLDS(src + j * 1024, dst + j * 1024);
  }

  // ---- A fragments: 32 rows x 256 dims bf16, resident (64 VGPR) ----
  // A map: row = lane&15 (+rf*16+rg*32), k = (lane>>4)*8 + j (+ks*32)
  bf16x8 A[2][8];
  #pragma unroll
  for (int rf = 0; rf < 2; ++rf) {
    const int t = tbase + rg * 32 + rf * 16 + l15;
    const float* lp = latb + t;
    #pragma unroll
    for (int ks = 0; ks < 8; ++ks) {
      const int c0 = ks * 32 + kg * 8;
      bf16x8 a;
      #pragma unroll
      for (int j = 0; j < 8; ++j)
        a[j] = (short)f2bf(lp[(size_t)(c0 + j) * T_]);   // coalesced across l15
      A[rf][ks] = a;
    }
  }
  __syncthreads();   // drains chunk-0 DMA

  unsigned m1[8], m2[8];
  #pragma unroll
  for (int s = 0; s < 8; ++s) { m1[s] = 0u; m2[s] = 0u; }
  const unsigned kv0 = cg * 32 + l15;

  for (int ch = 0; ch < NCHUNK; ++ch) {
    const int pb = ch & 1;
    if (ch + 1 < NCHUNK) {       // prefetch next chunk into other buffer
      const unsigned char* src =
          ebf + (size_t)(ch + 1) * (CHUNK * 512) + w * 8192 + lane * 16;
      unsigned char* dst = &Ebuf[pb ^ 1][w * 8192];
      #pragma unroll
      for (int j = 0; j < 8; ++j) GLDS(src + j * 1024, dst + j * 1024);
    }

    // B fragments: col = lane&15, k = (lane>>4)*8+j — swizzled, conflict-free
    const unsigned char* bbase = &Ebuf[pb][0];
    #pragma unroll
    for (int cf = 0; cf < 2; ++cf) {
      const int code_l = cg * 32 + cf * 16 + l15;
      bf16x8 Bf[8];
      #pragma unroll
      for (int ks = 0; ks < 8; ++ks) {
        const unsigned off = code_l * 512 + ((ks * 64 + kg * 16) ^ (l15 << 4));
        Bf[ks] = *reinterpret_cast<const bf16x8*>(bbase + off);
      }
      const unsigned kv = kv0 + (unsigned)(ch * CHUNK + cf * 16);
      #pragma unroll
      for (int rf = 0; rf < 2; ++rf) {
        f32x4 acc = {BIASF, BIASF, BIASF, BIASF};   // BIAS folded into C-init
        #pragma unroll
        for (int ks = 0; ks < 8; ++ks)
          acc = __builtin_amdgcn_mfma_f32_16x16x32_bf16(A[rf][ks], Bf[ks],
                                                        acc, 0, 0, 0);
        #pragma unroll
        for (int r = 0; r < 4; ++r) {   // C: col=lane&15, row=(lane>>4)*4+r
          const unsigned p = (__float_as_uint(acc[r]) & 0xFFFFE000u) | kv;
          const int s = rf * 4 + r;
          const unsigned mn = umin_(p, m1[s]);
          m1[s] = umax_(p, m1[s]);
          m2[s] = umax_(m2[s], mn);
        }
      }
    }
    __syncthreads();   // drain DMA(ch+1), release Ebuf[pb]
  }

  // ---- row max: reduce over lane&15 (16 lanes hold same row set) ----
  #pragma unroll
  for (int s = 0; s < 8; ++s) {
    unsigned v = m1[s];
    v = umax_(v, __shfl_xor(v, 1));
    v = umax_(v, __shfl_xor(v, 2));
    v = umax_(v, __shfl_xor(v, 4));
    v = umax_(v, __shfl_xor(v, 8));
    const int row = rg * 32 + (s >> 2) * 16 + kg * 4 + (s & 3);
    rmaxU[cg][row] = v;                 // 16 lanes write same value: benign
  }
  __syncthreads();

  // ---- candidate emission (load-balanced worklist) ----
  #pragma unroll
  for (int s = 0; s < 8; ++s) {
    const int row = rg * 32 + (s >> 2) * 16 + kg * 4 + (s & 3);
    const unsigned rm = umax_(rmaxU[0][row], rmaxU[1][row]);
    const float thr = __uint_as_float(rm & 0xFFFFE000u) - MARGINF;
    #pragma unroll
    for (int which = 0; which < 2; ++which) {
      const unsigned m = which ? m2[s] : m1[s];
      if (__uint_as_float(m & 0xFFFFE000u) >= thr) {
        int id = atomicAdd(&qn, 1);
        if (id < QCAP) qlist[id] = ((unsigned)row << 13) | (m & 0x1FFFu);
      }
    }
  }
  __syncthreads();

  // ---- phase 2: exact refine, one candidate per lane ----
  const int nq = qn < QCAP ? qn : QCAP;
  for (int i = tid; i < nq; i += NTHR) {
    const unsigned e = qlist[i];
    const int row = (int)(e >> 13);
    const int k   = (int)(e & 0x1FFFu);
    const int t   = tbase + row;
    const float* xp = latb + t;
    const float* ep = emb + (size_t)k * D_;
    float x2 = 0.f, e2 = 0.f;
    double da = 0.0;
    {
      #pragma clang fp contract(off)
      for (int c = 0; c < D_; ++c) {
        const float xv = xp[(size_t)c * T_];
        const float ev = ep[c];
        const float xs = xv * xv; x2 = x2 + xs;   // sequential fp32, ref order
        const float es = ev * ev; e2 = e2 + es;
        da = fma((double)xv, (double)ev, da);
      }
    }
    float dist;
    {
      #pragma clang fp contract(off)
      const float mmf = (float)da;     // mm rounded to fp32
      const float tk  = x2 + e2;       // fl(x2 + e2)
      const float two = 2.0f * mmf;    // exact
      dist = tk - two;                 // final fp32 rounding
    }
    const unsigned long long pk =
        ((unsigned long long)__float_as_uint(dist) << 32) | (unsigned)k;
    atomicMin(&bestp[row], pk);        // first-index tie-break via low bits
  }
  __syncthreads();
  if (tid < BM) {
    const int k = (int)(bestp[tid] & 0xFFFFFFFFu);
    idx_out[n0 + tid]  = k;
    idxf_out[n0 + tid] = (float)k;     // float idx output folded in
  }
}

// ---------------------------------------------------------------------------
// Output gather + loss partials. Block = (b, 64-t chunk). The 64 needed emb
// rows are staged in LDS via fully-coalesced float4 reads (1KB bursts) into a
// [c][r] layout (+1 pad) so the write phase reads conflict-free; lat reads and
// outq writes stay coalesced over t.
// ---------------------------------------------------------------------------
__global__ __launch_bounds__(256) void vq_out_kernel(
    const float* __restrict__ lat, const float* __restrict__ emb,
    const int* __restrict__ idx, float* __restrict__ outq,
    double* __restrict__ partial)
{
  __shared__ float Ecol[256][65];      // [c][r], 66.6KB
  __shared__ double sred[256];
  const int gid = blockIdx.x;          // b(16) x tc(32)
  const int b   = gid >> 5;
  const int t0  = (gid & 31) * 64;

  // stage: 16 iters x 4 rows; r uniform per wave, c4 = lane
  {
    const int r4 = threadIdx.x >> 6, c4 = threadIdx.x & 63;
    for (int it = 0; it < 16; ++it) {
      const int r = it * 4 + r4;
      const int n = idx[b * T_ + t0 + r];
      const float4 v =
          *reinterpret_cast<const float4*>(emb + (size_t)n * D_ + c4 * 4);
      Ecol[c4 * 4 + 0][r] = v.x;
      Ecol[c4 * 4 + 1][r] = v.y;
      Ecol[c4 * 4 + 2][r] = v.z;
      Ecol[c4 * 4 + 3][r] = v.w;
    }
  }
  __syncthreads();

  const int cq = threadIdx.x >> 6, tl = threadIdx.x & 63;
  const int t  = t0 + tl;
  double lsum = 0.0;
  for (int ci = 0; ci < 64; ++ci) {
    const int c = cq * 64 + ci;
    const size_t off = ((size_t)b * C_ + c) * T_ + t;
    const float q = Ecol[c][tl];       // bank = (c + tl) % 32: conflict-free
    const float l = lat[off];
    outq[off] = q;
    const double d = (double)q - (double)l;
    lsum += d * d;
  }
  sred[threadIdx.x] = lsum;
  __syncthreads();
  for (int s = 128; s > 0; s >>= 1) {
    if (threadIdx.x < s) sred[threadIdx.x] += sred[threadIdx.x + s];
    __syncthreads();
  }
  if (threadIdx.x == 0) partial[gid] = sred[0];
}

__global__ __launch_bounds__(256) void vq_loss_kernel(
    const double* __restrict__ partial, float* __restrict__ out_loss)
{
  __shared__ double sred[256];
  double s = 0.0;
  for (int i = threadIdx.x; i < 512; i += 256) s += partial[i];
  sred[threadIdx.x] = s;
  __syncthreads();
  for (int st = 128; st > 0; st >>= 1) {
    if (threadIdx.x < st) sred[threadIdx.x] += sred[threadIdx.x + st];
    __syncthreads();
  }
  if (threadIdx.x == 0) {
    double m = sred[0] / (double)OUTQ;
    out_loss[0] = (float)(m + 0.25 * m);
  }
}

extern "C" void kernel_launch(void* const* d_in, const int* in_sizes, int n_in,
                              void* d_out, int out_size, void* d_ws, size_t ws_size,
                              hipStream_t stream)
{
  const float* lat = (const float*)d_in[0];   // [B, C, T] fp32
  const float* emb = (const float*)d_in[1];   // [K, D] fp32

  float* outq     = (float*)d_out;            // [B, C, T]
  float* out_loss = outq + OUTQ;              // scalar
  float* out_idx  = outq + OUTQ + 1;          // [B, T] as float

  // 4MB swizzled-bf16 E scratch overlaid on outq (dead before vq_out writes)
  unsigned char* ebf = (unsigned char*)d_out;
  // small scratch in ws: idx (128KB) + partials (4KB)
  int*    idx     = (int*)d_ws;
  double* partial = (double*)((char*)d_ws + (size_t)N_ * sizeof(int));

  ebf_prep_kernel  <<<2048,    256,  0, stream>>>(emb, ebf);
  vq_argmin_kernel <<<N_ / BM, NTHR, 0, stream>>>(lat, emb, ebf, idx, out_idx);
  vq_out_kernel    <<<512,     256,  0, stream>>>(lat, emb, idx, outq, partial);
  vq_loss_kernel   <<<1,       256,  0, stream>>>(partial, out_loss);
}